// Round 2
// baseline (243.009 us; speedup 1.0000x reference)
//
#include <hip/hip_runtime.h>

// GAT layer on MI355X. N=50000, E=800000 (+N self loops), DIN=256, DOUT=128, H=8.
//
//  r8: replaced the 196-block bucketing pipeline (bucket_pass -> pair_buf ->
//  fine_scatter) with a direct global-atomic CSR build at full parallelism.
//  r7's counters showed bp_gemm stuck at 43us with MfmaUtil 2.4 / VALU 4.4 /
//  HBM 13 / occ 12% and SQ_LDS_BANK_CONFLICT frozen at 178448 -- the serial
//  16-iter LDS-atomic loops of the 196-block bucket passes, not the GEMM.
//
//  K1 conv_w     : W_bf = bf16(W_trans); zeroes deg[]
//  K2 cnt_gemm   : [blocks 0..195]  count: atomicAdd(deg[dst]) per edge (~5us,
//                  hidden under gemm)
//                  [blocks 196..]   gemm: h_bf = bf16(x @ W^T), 16x16x32 MFMA,
//                  W staged once per block into 64 KiB LDS in MFMA fragment
//                  order -> hot-loop B reads are lane-linear ds_read_b128,
//                  conflict-free. One wave = 32 rows x 128 cols, x prefetched
//                  1 ks ahead. (r7 structure, measured -10us vs r6)
//  K3 fs_ns      : [blocks 0..195]  offsets: per-bucket block sums deg[0..node0)
//                  (L2-resident, coalesced) + wave scan of deg+1 -> offsets[],
//                  self-loop inject, cur[] cursor seed
//                  [blocks 196..]   node_scores: a_src/a_dst from h_bf
//  K4 scatter    : grid-stride over E: k = atomicAdd(cur[dst]); src_sorted[k]=src
//  K5 aggregate  : one wave per dst node, flat CSR, 8 edges per loop iter

constexpr int DIN  = 256;
constexpr int DOUT = 128;
constexpr int H    = 8;
constexpr int CHUNK = 4096;  // edges per count block

typedef __attribute__((ext_vector_type(8))) short bf16x8;
typedef __attribute__((ext_vector_type(4))) float f32x4;

__device__ __forceinline__ float lrelu(float s) { return s >= 0.0f ? s : 0.2f * s; }

__device__ __forceinline__ unsigned short f2bf(float f) {  // RNE
  unsigned u = __float_as_uint(f);
  u += 0x7FFF + ((u >> 16) & 1);
  return (unsigned short)(u >> 16);
}
__device__ __forceinline__ float bflo(unsigned u) { return __uint_as_float(u << 16); }
__device__ __forceinline__ float bfhi(unsigned u) { return __uint_as_float(u & 0xFFFF0000u); }

__device__ __forceinline__ int wave_incl_scan(int v, int lane) {
#pragma unroll
  for (int d = 1; d < 64; d <<= 1) {
    int t = __shfl_up(v, d, 64);
    if (lane >= d) v += t;
  }
  return v;
}

// ---------------- K1: W -> bf16 (+ zero deg) ----------------
__global__ void conv_w(const float* __restrict__ W, unsigned short* __restrict__ Wbf,
                       int n, int* __restrict__ deg, int N) {
  int i = blockIdx.x * blockDim.x + threadIdx.x;
  if (i < n) Wbf[i] = f2bf(W[i]);
  if (i < N) deg[i] = 0;
}

// ---------------- K2: fused degree-count + GEMM ----------------
// gemm wave: 32 rows x 128 cols. A-frag lane(mr,kg) holds
// A[m0+mt*16+mr][ks*32+kg*8..+8); C/D: col = lane&15, row = kg*4 + reg.
// B fragments come from LDS (fragment-ordered stage of Wbf, 64 KiB).
__global__ __launch_bounds__(256, 2) void cnt_gemm(const float* __restrict__ x,
                                                   const unsigned short* __restrict__ Wbf,
                                                   unsigned short* __restrict__ hbf, int N,
                                                   const int* __restrict__ ei,
                                                   int* __restrict__ deg,
                                                   int E, int bp_blocks) {
  __shared__ __align__(16) unsigned short Wlds[DOUT * DIN];  // 64 KiB
  if ((int)blockIdx.x < bp_blocks) {
    // ---- degree count (4096 edges per block, pure global atomics) ----
    int c0 = blockIdx.x * CHUNK;
#pragma unroll
    for (int q = 0; q < 16; ++q) {
      int e = c0 + q * 256 + threadIdx.x;
      if (e < E) atomicAdd(&deg[ei[E + e]], 1);
    }
    return;
  }
  // ---- GEMM ----
  // Stage W into LDS in fragment order: chunk c = (t*8+ks)*64 + L holds
  // Wbf[(t*16 + (L&15))*DIN + ks*32 + (L>>4)*8 .. +8). Hot-loop ds_read_b128
  // is then lane-linear (base + lane*16 + imm), conflict-free.
  {
    const int tid = threadIdx.x;
#pragma unroll
    for (int i = 0; i < 16; ++i) {
      int c = i * 256 + tid;                 // chunk 0..4095
      int t = c >> 9, ks = (c >> 6) & 7, L = c & 63;
      const unsigned short* gp = Wbf + ((t * 16 + (L & 15)) * DIN + ks * 32 + (L >> 4) * 8);
      *(bf16x8*)&Wlds[c * 8] = *(const bf16x8*)gp;
    }
  }
  __syncthreads();
  int wid = ((int)blockIdx.x - bp_blocks) * 4 + (threadIdx.x >> 6);
  int m0 = wid * 32;
  if (m0 >= N) return;
  int lane = threadIdx.x & 63;
  int mr = lane & 15, kg = lane >> 4;
  int r0 = m0 + mr;       if (r0 >= N) r0 = N - 1;  // clamp (stores guarded)
  int r1 = m0 + 16 + mr;  if (r1 >= N) r1 = N - 1;
  const float* xr0 = x + (size_t)r0 * DIN + kg * 8;
  const float* xr1 = x + (size_t)r1 * DIN + kg * 8;
  const unsigned short* fb = Wlds + lane * 8;  // lane's fragment base

  f32x4 acc[2][8];
#pragma unroll
  for (int mt = 0; mt < 2; ++mt)
#pragma unroll
    for (int t = 0; t < 8; ++t) acc[mt][t] = (f32x4){0.f, 0.f, 0.f, 0.f};

  float4 p00 = *(const float4*)xr0, p01 = *(const float4*)(xr0 + 4);
  float4 p10 = *(const float4*)xr1, p11 = *(const float4*)(xr1 + 4);
#pragma unroll
  for (int ks = 0; ks < 8; ++ks) {
    bf16x8 a0, a1;
    a0[0] = (short)f2bf(p00.x); a0[1] = (short)f2bf(p00.y);
    a0[2] = (short)f2bf(p00.z); a0[3] = (short)f2bf(p00.w);
    a0[4] = (short)f2bf(p01.x); a0[5] = (short)f2bf(p01.y);
    a0[6] = (short)f2bf(p01.z); a0[7] = (short)f2bf(p01.w);
    a1[0] = (short)f2bf(p10.x); a1[1] = (short)f2bf(p10.y);
    a1[2] = (short)f2bf(p10.z); a1[3] = (short)f2bf(p10.w);
    a1[4] = (short)f2bf(p11.x); a1[5] = (short)f2bf(p11.y);
    a1[6] = (short)f2bf(p11.z); a1[7] = (short)f2bf(p11.w);
    if (ks < 7) {  // prefetch next ks while MFMAs run
      p00 = *(const float4*)(xr0 + (ks + 1) * 32);
      p01 = *(const float4*)(xr0 + (ks + 1) * 32 + 4);
      p10 = *(const float4*)(xr1 + (ks + 1) * 32);
      p11 = *(const float4*)(xr1 + (ks + 1) * 32 + 4);
    }
#pragma unroll
    for (int t = 0; t < 8; ++t) {
      bf16x8 b = *(const bf16x8*)(fb + ((t * 8 + ks) << 9));  // imm offset
      acc[0][t] = __builtin_amdgcn_mfma_f32_16x16x32_bf16(a0, b, acc[0][t], 0, 0, 0);
      acc[1][t] = __builtin_amdgcn_mfma_f32_16x16x32_bf16(a1, b, acc[1][t], 0, 0, 0);
    }
  }
#pragma unroll
  for (int mt = 0; mt < 2; ++mt)
#pragma unroll
    for (int t = 0; t < 8; ++t)
#pragma unroll
      for (int r = 0; r < 4; ++r) {
        int row = m0 + mt * 16 + kg * 4 + r;
        if (row < N) hbf[(size_t)row * DOUT + t * 16 + mr] = f2bf(acc[mt][t][r]);
      }
}

// ---------------- K3: fused offsets-build + node_scores ----------------
__global__ __launch_bounds__(256) void fs_ns(const int* __restrict__ deg,
                                             int* __restrict__ offsets,
                                             int* __restrict__ cur,
                                             unsigned short* __restrict__ src_sorted,
                                             const unsigned short* __restrict__ hbf,
                                             const float* __restrict__ Wa,
                                             float* __restrict__ a_src,
                                             float* __restrict__ a_dst,
                                             int N, int E, int nb) {
  __shared__ int redS[256];
  __shared__ int wsumS[4];
  const int t = threadIdx.x;
  if ((int)blockIdx.x >= nb) {
    // ---- node_scores ----
    int idx = ((int)blockIdx.x - nb) * 256 + t;
    if (idx >= N * H) return;
    int v = idx >> 3, hh = idx & 7;
    const unsigned short* hp = hbf + (size_t)v * DOUT + hh * 16;
    uint4 p0 = *(const uint4*)hp;
    uint4 p1 = *(const uint4*)(hp + 8);
    float hv[16];
    hv[0] = bflo(p0.x); hv[1] = bfhi(p0.x); hv[2] = bflo(p0.y); hv[3] = bfhi(p0.y);
    hv[4] = bflo(p0.z); hv[5] = bfhi(p0.z); hv[6] = bflo(p0.w); hv[7] = bfhi(p0.w);
    hv[8] = bflo(p1.x); hv[9] = bfhi(p1.x); hv[10] = bflo(p1.y); hv[11] = bfhi(p1.y);
    hv[12] = bflo(p1.z); hv[13] = bfhi(p1.z); hv[14] = bflo(p1.w); hv[15] = bfhi(p1.w);
    float s1 = 0.f, s2 = 0.f;
#pragma unroll
    for (int d = 0; d < 16; ++d) {
      s1 += hv[d] * Wa[d];
      s2 += hv[d] * Wa[16 + d];
    }
    a_src[idx] = s1;
    a_dst[idx] = s2;
    return;
  }
  // ---- offsets build: one block per 256-node bucket ----
  const int B = blockIdx.x;
  const int node0 = B * 256;
  const int v = node0 + t;
  const int valid = (v < N);
  // csr_base = node0 (self loops before this bucket) + sum deg[0..node0)
  // deg is 200 KB -> L2-resident; coalesced stride-256 reads, B iters/thread.
  int part = 0;
  for (int j = t; j < node0; j += 256) part += deg[j];
  redS[t] = part;
  __syncthreads();
  for (int s = 128; s > 0; s >>= 1) {
    if (t < s) redS[t] += redS[t + s];
    __syncthreads();
  }
  const int csr_base = redS[0] + node0;
  int val = valid ? deg[v] + 1 : 0;  // +1 = self loop
  int lane = t & 63, wv = t >> 6;
  int inc = wave_incl_scan(val, lane);
  if (lane == 63) wsumS[wv] = inc;
  __syncthreads();
  int base = 0;
  for (int q = 0; q < wv; ++q) base += wsumS[q];
  int ex = base + inc - val;
  if (valid) {
    offsets[v] = csr_base + ex;
    src_sorted[csr_base + ex] = (unsigned short)v;  // self loop at slot 0
    cur[v] = csr_base + ex + 1;                     // edges fill after
  }
  if (B == 0 && t == 0) offsets[N] = E + N;
}

// ---------------- K4: edge scatter into CSR ----------------
__global__ __launch_bounds__(256) void scatter(const int* __restrict__ ei,
                                               int* __restrict__ cur,
                                               unsigned short* __restrict__ src_sorted,
                                               int E) {
  int i0 = blockIdx.x * blockDim.x + threadIdx.x;
  int stride = gridDim.x * blockDim.x;
  for (int e = i0; e < E; e += stride) {
    int s = ei[e];
    int d = ei[E + e];
    int k = atomicAdd(&cur[d], 1);
    src_sorted[k] = (unsigned short)s;
  }
}

// ---------------- K5: aggregation, flat CSR, 8 edges per iter ----------------
// One wave per dst node. Group g = lane>>4 handles edges j0+g and j0+4+g
// (two independent gather chains in flight); sub-lane sl = lane&15 covers
// cols [sl*8, sl*8+8) (16B uint4 load); head = sl>>1.
__global__ __launch_bounds__(256) void aggregate(const unsigned short* __restrict__ hbf,
                                                 const float* __restrict__ a_src,
                                                 const float* __restrict__ a_dst,
                                                 const float* __restrict__ b_att,
                                                 const int* __restrict__ offsets,
                                                 const unsigned short* __restrict__ src_sorted,
                                                 float* __restrict__ out, int N) {
  int wid = blockIdx.x * 4 + (threadIdx.x >> 6);
  if (wid >= N) return;
  int lane = threadIdx.x & 63;
  int g = lane >> 4, sl = lane & 15;
  int head = sl >> 1;
  float adv = a_dst[wid * H + head] + b_att[0];
  int beg = offsets[wid], end = offsets[wid + 1];
  float a0 = 0, a1 = 0, a2 = 0, a3 = 0, a4 = 0, a5 = 0, a6 = 0, a7 = 0, den = 0;
  for (int j0 = beg; j0 < end; j0 += 8) {
    int ja = j0 + g, jb = j0 + 4 + g;
    bool va = ja < end, vb = jb < end;
    int sa = src_sorted[va ? ja : beg];
    int sb = src_sorted[vb ? jb : beg];
    float asa = a_src[sa * H + head];
    float asb = a_src[sb * H + head];
    uint4 ua = *(const uint4*)(hbf + sa * DOUT + sl * 8);
    uint4 ub = *(const uint4*)(hbf + sb * DOUT + sl * 8);
    float ea = va ? __expf(lrelu(asa + adv)) : 0.f;
    float eb = vb ? __expf(lrelu(asb + adv)) : 0.f;
    den += ea + eb;
    a0 += ea * bflo(ua.x) + eb * bflo(ub.x);
    a1 += ea * bfhi(ua.x) + eb * bfhi(ub.x);
    a2 += ea * bflo(ua.y) + eb * bflo(ub.y);
    a3 += ea * bfhi(ua.y) + eb * bfhi(ub.y);
    a4 += ea * bflo(ua.z) + eb * bflo(ub.z);
    a5 += ea * bfhi(ua.z) + eb * bfhi(ub.z);
    a6 += ea * bflo(ua.w) + eb * bflo(ub.w);
    a7 += ea * bfhi(ua.w) + eb * bfhi(ub.w);
  }
  den += __shfl_xor(den, 16, 64); den += __shfl_xor(den, 32, 64);
  a0 += __shfl_xor(a0, 16, 64); a0 += __shfl_xor(a0, 32, 64);
  a1 += __shfl_xor(a1, 16, 64); a1 += __shfl_xor(a1, 32, 64);
  a2 += __shfl_xor(a2, 16, 64); a2 += __shfl_xor(a2, 32, 64);
  a3 += __shfl_xor(a3, 16, 64); a3 += __shfl_xor(a3, 32, 64);
  a4 += __shfl_xor(a4, 16, 64); a4 += __shfl_xor(a4, 32, 64);
  a5 += __shfl_xor(a5, 16, 64); a5 += __shfl_xor(a5, 32, 64);
  a6 += __shfl_xor(a6, 16, 64); a6 += __shfl_xor(a6, 32, 64);
  a7 += __shfl_xor(a7, 16, 64); a7 += __shfl_xor(a7, 32, 64);
  float inv = 1.0f / den;
  if (g == 0) {
    float4 o = make_float4(a0 * inv, a1 * inv, a2 * inv, a3 * inv);
    *(float4*)&out[wid * DOUT + sl * 8] = o;
  } else if (g == 1) {
    float4 o = make_float4(a4 * inv, a5 * inv, a6 * inv, a7 * inv);
    *(float4*)&out[wid * DOUT + sl * 8 + 4] = o;
  }
}

extern "C" void kernel_launch(void* const* d_in, const int* in_sizes, int n_in,
                              void* d_out, int out_size, void* d_ws, size_t ws_size,
                              hipStream_t stream) {
  const float* x     = (const float*)d_in[0];
  const float* W     = (const float*)d_in[1];
  const float* Wa    = (const float*)d_in[2];
  const float* b_att = (const float*)d_in[3];
  const int*   ei    = (const int*)d_in[4];
  const int N  = in_sizes[0] / DIN;
  const int E  = in_sizes[4] / 2;
  const int NB = (N + 255) / 256;  // 196 buckets
  float* out = (float*)d_out;

  char* p = (char*)d_ws;
  auto take = [&p](size_t bytes) {
    uintptr_t u = ((uintptr_t)p + 15) & ~(uintptr_t)15;
    p = (char*)(u + bytes);
    return (void*)u;
  };
  unsigned short* hbf = (unsigned short*)take((size_t)N * DOUT * 2);
  unsigned short* Wbf = (unsigned short*)take((size_t)DOUT * DIN * 2);
  float* a_src        = (float*)take((size_t)N * H * 4);
  float* a_dst        = (float*)take((size_t)N * H * 4);
  int* deg            = (int*)take((size_t)N * 4);
  int* cur            = (int*)take((size_t)N * 4);
  int* offsets        = (int*)take((size_t)(N + 1) * 4);
  unsigned short* src_sorted = (unsigned short*)take((size_t)(E + N + 16) * 2);

  dim3 b256(256);
  const int cw_blocks   = (N > DOUT * DIN ? N + 255 : DOUT * DIN + 255) / 256;
  const int bp_blocks   = (E + CHUNK - 1) / CHUNK;        // 196
  const int gemm_blocks = ((N + 31) / 32 + 3) / 4;        // 391 (4 waves x 32 rows)
  const int ns_blocks   = (N * H + 255) / 256;            // 1563

  conv_w<<<dim3(cw_blocks), b256, 0, stream>>>(W, Wbf, DOUT * DIN, deg, N);
  cnt_gemm<<<dim3(bp_blocks + gemm_blocks), b256, 0, stream>>>(
      x, Wbf, hbf, N, ei, deg, E, bp_blocks);
  fs_ns<<<dim3(NB + ns_blocks), b256, 0, stream>>>(
      deg, offsets, cur, src_sorted, hbf, Wa, a_src, a_dst, N, E, NB);
  scatter<<<dim3(1024), b256, 0, stream>>>(ei, cur, src_sorted, E);
  aggregate<<<dim3((N + 3) / 4), b256, 0, stream>>>(hbf, a_src, a_dst, b_att, offsets,
                                                    src_sorted, out, N);
}

// Round 3
// 169.843 us; speedup vs baseline: 1.4308x; 1.4308x over previous
//
#include <hip/hip_runtime.h>

// GAT layer on MI355X. N=50000, E=800000 (+N self loops), DIN=256, DOUT=128, H=8.
//
//  r9: revert r8's global-atomic CSR build (atomics caused HBM RMW traffic:
//  WRITE_SIZE 17->37MB, scatter 56us, cnt_gemm 53us). Back to r7's LDS-hist
//  bucketing, plus: CHUNK 4096->2048 (bp work over ~196 CUs instead of 98,
//  since every block of the fused kernel reserves 64KiB LDS -> 2 blocks/CU),
//  4-way ILP batching in fine_scatter's serialized atomic->store loops, and
//  src-index software pipelining in aggregate.
//
//  K1 conv_w     : W_bf = bf16(W_trans); zeroes per-bucket counters
//  K2 bp_gemm    : [blocks 0..390]  bucket_pass: edges -> per-256-node-bucket
//                  regions (atomic cursors, packed u32 = src<<8 | dst&255)
//                  [blocks 391..]   gemm: h_bf = bf16(x @ W^T), 16x16x32 MFMA,
//                  W staged once per block into 64 KiB LDS in MFMA fragment
//                  order -> hot-loop B reads lane-linear ds_read_b128,
//                  conflict-free. One wave = 32 rows x 128 cols.
//  K3 fs_ns      : [blocks 0..195]  fine_scatter: one block per bucket, per-dst
//                  LDS hist+scan -> offsets[], self-loop inject, ushort CSR
//                  [blocks 196..]   node_scores: a_src/a_dst from h_bf
//  K4 aggregate  : one wave per dst node, flat CSR, 8 edges per loop iter,
//                  next-iter src indices prefetched

constexpr int DIN  = 256;
constexpr int DOUT = 128;
constexpr int H    = 8;
constexpr int CAP  = 5120;   // pair_buf slots per bucket (mean 4096, +16 sigma)
constexpr int CHUNK = 2048;  // edges per bucket_pass block (r9: spread CUs)

typedef __attribute__((ext_vector_type(8))) short bf16x8;
typedef __attribute__((ext_vector_type(4))) float f32x4;

__device__ __forceinline__ float lrelu(float s) { return s >= 0.0f ? s : 0.2f * s; }

__device__ __forceinline__ unsigned short f2bf(float f) {  // RNE
  unsigned u = __float_as_uint(f);
  u += 0x7FFF + ((u >> 16) & 1);
  return (unsigned short)(u >> 16);
}
__device__ __forceinline__ float bflo(unsigned u) { return __uint_as_float(u << 16); }
__device__ __forceinline__ float bfhi(unsigned u) { return __uint_as_float(u & 0xFFFF0000u); }

__device__ __forceinline__ int wave_incl_scan(int v, int lane) {
#pragma unroll
  for (int d = 1; d < 64; d <<= 1) {
    int t = __shfl_up(v, d, 64);
    if (lane >= d) v += t;
  }
  return v;
}

// ---------------- K1: W -> bf16 (+ zero bucket counters) ----------------
__global__ void conv_w(const float* __restrict__ W, unsigned short* __restrict__ Wbf,
                       int n, int* __restrict__ bcount, int nb) {
  int i = blockIdx.x * blockDim.x + threadIdx.x;
  if (i < n) Wbf[i] = f2bf(W[i]);
  if (blockIdx.x == 0 && threadIdx.x < nb) bcount[threadIdx.x] = 0;
}

// ---------------- K2: fused bucket_pass + GEMM ----------------
// gemm wave: 32 rows x 128 cols. A-frag lane(mr,kg) holds
// A[m0+mt*16+mr][ks*32+kg*8..+8); C/D: col = lane&15, row = kg*4 + reg.
// B fragments come from LDS (fragment-ordered stage of Wbf, 64 KiB).
__global__ __launch_bounds__(256, 2) void bp_gemm(const float* __restrict__ x,
                                                  const unsigned short* __restrict__ Wbf,
                                                  unsigned short* __restrict__ hbf, int N,
                                                  const int* __restrict__ ei,
                                                  int* __restrict__ bcount,
                                                  unsigned* __restrict__ pair_buf,
                                                  int E, int nb, int bp_blocks) {
  __shared__ __align__(16) unsigned short Wlds[DOUT * DIN];  // 64 KiB
  if ((int)blockIdx.x < bp_blocks) {
    // ---- bucket_pass (2048 edges per block); overlay hist/gbase on Wlds ----
    int* hist  = (int*)Wlds;
    int* gbase = hist + 256;
    int c0 = blockIdx.x * CHUNK;
    hist[threadIdx.x] = 0;
    __syncthreads();
    int dcache[8];
#pragma unroll
    for (int q = 0; q < 8; ++q) {
      int e = c0 + q * 256 + threadIdx.x;
      dcache[q] = (e < E) ? ei[E + e] : -1;
      if (dcache[q] >= 0) atomicAdd(&hist[dcache[q] >> 8], 1);
    }
    __syncthreads();
    if (threadIdx.x < nb) {
      int c = hist[threadIdx.x];
      gbase[threadIdx.x] = c ? atomicAdd(&bcount[threadIdx.x], c) : 0;
    }
    __syncthreads();
    hist[threadIdx.x] = 0;  // reuse as local rank cursor
    __syncthreads();
    int scache[8];
#pragma unroll
    for (int q = 0; q < 8; ++q) {  // prefetch src indices (independent loads)
      int e = c0 + q * 256 + threadIdx.x;
      scache[q] = (dcache[q] >= 0) ? ei[e] : 0;
    }
#pragma unroll
    for (int q = 0; q < 8; ++q) {
      if (dcache[q] >= 0) {
        int bk = dcache[q] >> 8;
        int r = atomicAdd(&hist[bk], 1);
        pair_buf[bk * CAP + gbase[bk] + r] =
            ((unsigned)scache[q] << 8) | (unsigned)(dcache[q] & 255);
      }
    }
    return;
  }
  // ---- GEMM ----
  // Stage W into LDS in fragment order: chunk c = (t*8+ks)*64 + L holds
  // Wbf[(t*16 + (L&15))*DIN + ks*32 + (L>>4)*8 .. +8). Hot-loop ds_read_b128
  // is then lane-linear (base + lane*16 + imm), conflict-free.
  {
    const int tid = threadIdx.x;
#pragma unroll
    for (int i = 0; i < 16; ++i) {
      int c = i * 256 + tid;                 // chunk 0..4095
      int t = c >> 9, ks = (c >> 6) & 7, L = c & 63;
      const unsigned short* gp = Wbf + ((t * 16 + (L & 15)) * DIN + ks * 32 + (L >> 4) * 8);
      *(bf16x8*)&Wlds[c * 8] = *(const bf16x8*)gp;
    }
  }
  __syncthreads();
  int wid = ((int)blockIdx.x - bp_blocks) * 4 + (threadIdx.x >> 6);
  int m0 = wid * 32;
  if (m0 >= N) return;
  int lane = threadIdx.x & 63;
  int mr = lane & 15, kg = lane >> 4;
  int r0 = m0 + mr;       if (r0 >= N) r0 = N - 1;  // clamp (stores guarded)
  int r1 = m0 + 16 + mr;  if (r1 >= N) r1 = N - 1;
  const float* xr0 = x + (size_t)r0 * DIN + kg * 8;
  const float* xr1 = x + (size_t)r1 * DIN + kg * 8;
  const unsigned short* fb = Wlds + lane * 8;  // lane's fragment base

  f32x4 acc[2][8];
#pragma unroll
  for (int mt = 0; mt < 2; ++mt)
#pragma unroll
    for (int t = 0; t < 8; ++t) acc[mt][t] = (f32x4){0.f, 0.f, 0.f, 0.f};

  float4 p00 = *(const float4*)xr0, p01 = *(const float4*)(xr0 + 4);
  float4 p10 = *(const float4*)xr1, p11 = *(const float4*)(xr1 + 4);
#pragma unroll
  for (int ks = 0; ks < 8; ++ks) {
    bf16x8 a0, a1;
    a0[0] = (short)f2bf(p00.x); a0[1] = (short)f2bf(p00.y);
    a0[2] = (short)f2bf(p00.z); a0[3] = (short)f2bf(p00.w);
    a0[4] = (short)f2bf(p01.x); a0[5] = (short)f2bf(p01.y);
    a0[6] = (short)f2bf(p01.z); a0[7] = (short)f2bf(p01.w);
    a1[0] = (short)f2bf(p10.x); a1[1] = (short)f2bf(p10.y);
    a1[2] = (short)f2bf(p10.z); a1[3] = (short)f2bf(p10.w);
    a1[4] = (short)f2bf(p11.x); a1[5] = (short)f2bf(p11.y);
    a1[6] = (short)f2bf(p11.z); a1[7] = (short)f2bf(p11.w);
    if (ks < 7) {  // prefetch next ks while MFMAs run
      p00 = *(const float4*)(xr0 + (ks + 1) * 32);
      p01 = *(const float4*)(xr0 + (ks + 1) * 32 + 4);
      p10 = *(const float4*)(xr1 + (ks + 1) * 32);
      p11 = *(const float4*)(xr1 + (ks + 1) * 32 + 4);
    }
#pragma unroll
    for (int t = 0; t < 8; ++t) {
      bf16x8 b = *(const bf16x8*)(fb + ((t * 8 + ks) << 9));  // imm offset
      acc[0][t] = __builtin_amdgcn_mfma_f32_16x16x32_bf16(a0, b, acc[0][t], 0, 0, 0);
      acc[1][t] = __builtin_amdgcn_mfma_f32_16x16x32_bf16(a1, b, acc[1][t], 0, 0, 0);
    }
  }
#pragma unroll
  for (int mt = 0; mt < 2; ++mt)
#pragma unroll
    for (int t = 0; t < 8; ++t)
#pragma unroll
      for (int r = 0; r < 4; ++r) {
        int row = m0 + mt * 16 + kg * 4 + r;
        if (row < N) hbf[(size_t)row * DOUT + t * 16 + mr] = f2bf(acc[mt][t][r]);
      }
}

// ---------------- K3: fused fine_scatter + node_scores ----------------
__global__ __launch_bounds__(256) void fs_ns(const unsigned* __restrict__ pair_buf,
                                             const int* __restrict__ bcount,
                                             int* __restrict__ offsets,
                                             unsigned short* __restrict__ src_sorted,
                                             const unsigned short* __restrict__ hbf,
                                             const float* __restrict__ Wa,
                                             float* __restrict__ a_src,
                                             float* __restrict__ a_dst,
                                             int N, int E, int nb) {
  __shared__ int cnt[256];
  __shared__ int cur[256];
  __shared__ int redS[256];
  __shared__ int wsumS[4];
  const int t = threadIdx.x;
  if ((int)blockIdx.x >= nb) {
    // ---- node_scores ----
    int idx = ((int)blockIdx.x - nb) * 256 + t;
    if (idx >= N * H) return;
    int v = idx >> 3, hh = idx & 7;
    const unsigned short* hp = hbf + (size_t)v * DOUT + hh * 16;
    uint4 p0 = *(const uint4*)hp;
    uint4 p1 = *(const uint4*)(hp + 8);
    float hv[16];
    hv[0] = bflo(p0.x); hv[1] = bfhi(p0.x); hv[2] = bflo(p0.y); hv[3] = bfhi(p0.y);
    hv[4] = bflo(p0.z); hv[5] = bfhi(p0.z); hv[6] = bflo(p0.w); hv[7] = bfhi(p0.w);
    hv[8] = bflo(p1.x); hv[9] = bfhi(p1.x); hv[10] = bflo(p1.y); hv[11] = bfhi(p1.y);
    hv[12] = bflo(p1.z); hv[13] = bfhi(p1.z); hv[14] = bflo(p1.w); hv[15] = bfhi(p1.w);
    float s1 = 0.f, s2 = 0.f;
#pragma unroll
    for (int d = 0; d < 16; ++d) {
      s1 += hv[d] * Wa[d];
      s2 += hv[d] * Wa[16 + d];
    }
    a_src[idx] = s1;
    a_dst[idx] = s2;
    return;
  }
  // ---- fine_scatter: one block per bucket (256 nodes) ----
  const int B = blockIdx.x;
  const int node0 = B * 256;
  const int v = node0 + t;
  const int valid = (v < N);
  cnt[t] = valid ? 1 : 0;  // self loop
  __syncthreads();
  const int cntE = bcount[B];
  const unsigned* reg = pair_buf + B * CAP;
  // pass 1: per-dst histogram, 4-way ILP batches
  {
    int i = t;
    for (; i + 768 < cntE; i += 1024) {
      unsigned p0 = reg[i], p1 = reg[i + 256], p2 = reg[i + 512], p3 = reg[i + 768];
      atomicAdd(&cnt[p0 & 255], 1);
      atomicAdd(&cnt[p1 & 255], 1);
      atomicAdd(&cnt[p2 & 255], 1);
      atomicAdd(&cnt[p3 & 255], 1);
    }
    for (; i < cntE; i += 256) atomicAdd(&cnt[reg[i] & 255], 1);
  }
  // bucket edge base = sum of earlier bucket counts
  redS[t] = (t < B) ? bcount[t] : 0;
  __syncthreads();
  for (int s = 128; s > 0; s >>= 1) {
    if (t < s) redS[t] += redS[t + s];
    __syncthreads();
  }
  const int csr_base = redS[0] + node0;  // edges + self loops before this bucket
  int val = cnt[t];
  int lane = t & 63, wv = t >> 6;
  int inc = wave_incl_scan(val, lane);
  if (lane == 63) wsumS[wv] = inc;
  __syncthreads();
  int base = 0;
  for (int q = 0; q < wv; ++q) base += wsumS[q];
  int ex = base + inc - val;
  cur[t] = ex + 1;  // slot 0 = self loop
  if (valid) {
    offsets[v] = csr_base + ex;
    src_sorted[csr_base + ex] = (unsigned short)v;  // self loop
  }
  if (B == 0 && t == 0) offsets[N] = E + N;
  __syncthreads();
  // pass 2: scatter, 4-way ILP batches (atomics first, then dependent stores)
  {
    int i = t;
    for (; i + 768 < cntE; i += 1024) {
      unsigned p0 = reg[i], p1 = reg[i + 256], p2 = reg[i + 512], p3 = reg[i + 768];
      int k0 = atomicAdd(&cur[p0 & 255], 1);
      int k1 = atomicAdd(&cur[p1 & 255], 1);
      int k2 = atomicAdd(&cur[p2 & 255], 1);
      int k3 = atomicAdd(&cur[p3 & 255], 1);
      src_sorted[csr_base + k0] = (unsigned short)(p0 >> 8);
      src_sorted[csr_base + k1] = (unsigned short)(p1 >> 8);
      src_sorted[csr_base + k2] = (unsigned short)(p2 >> 8);
      src_sorted[csr_base + k3] = (unsigned short)(p3 >> 8);
    }
    for (; i < cntE; i += 256) {
      unsigned p = reg[i];
      int k = atomicAdd(&cur[p & 255], 1);
      src_sorted[csr_base + k] = (unsigned short)(p >> 8);
    }
  }
}

// ---------------- K4: aggregation, flat CSR, 8 edges per iter ----------------
// One wave per dst node. Group g = lane>>4 handles edges j0+g and j0+4+g;
// next iteration's src indices are prefetched (removes one latency level).
// Sub-lane sl = lane&15 covers cols [sl*8, sl*8+8); head = sl>>1.
__global__ __launch_bounds__(256) void aggregate(const unsigned short* __restrict__ hbf,
                                                 const float* __restrict__ a_src,
                                                 const float* __restrict__ a_dst,
                                                 const float* __restrict__ b_att,
                                                 const int* __restrict__ offsets,
                                                 const unsigned short* __restrict__ src_sorted,
                                                 float* __restrict__ out, int N) {
  int wid = blockIdx.x * 4 + (threadIdx.x >> 6);
  if (wid >= N) return;
  int lane = threadIdx.x & 63;
  int g = lane >> 4, sl = lane & 15;
  int head = sl >> 1;
  float adv = a_dst[wid * H + head] + b_att[0];
  int beg = offsets[wid], end = offsets[wid + 1];
  float a0 = 0, a1 = 0, a2 = 0, a3 = 0, a4 = 0, a5 = 0, a6 = 0, a7 = 0, den = 0;
  int ja = beg + g, jb = beg + 4 + g;
  int sa = src_sorted[ja < end ? ja : beg];
  int sb = src_sorted[jb < end ? jb : beg];
  for (int j0 = beg; j0 < end; j0 += 8) {
    int ja2 = j0 + 8 + g, jb2 = j0 + 12 + g;
    int sa2 = src_sorted[ja2 < end ? ja2 : beg];  // prefetch next iter
    int sb2 = src_sorted[jb2 < end ? jb2 : beg];
    bool va = (j0 + g) < end, vb = (j0 + 4 + g) < end;
    float asa = a_src[sa * H + head];
    float asb = a_src[sb * H + head];
    uint4 ua = *(const uint4*)(hbf + sa * DOUT + sl * 8);
    uint4 ub = *(const uint4*)(hbf + sb * DOUT + sl * 8);
    float ea = va ? __expf(lrelu(asa + adv)) : 0.f;
    float eb = vb ? __expf(lrelu(asb + adv)) : 0.f;
    den += ea + eb;
    a0 += ea * bflo(ua.x) + eb * bflo(ub.x);
    a1 += ea * bfhi(ua.x) + eb * bfhi(ub.x);
    a2 += ea * bflo(ua.y) + eb * bflo(ub.y);
    a3 += ea * bfhi(ua.y) + eb * bfhi(ub.y);
    a4 += ea * bflo(ua.z) + eb * bflo(ub.z);
    a5 += ea * bfhi(ua.z) + eb * bfhi(ub.z);
    a6 += ea * bflo(ua.w) + eb * bflo(ub.w);
    a7 += ea * bfhi(ua.w) + eb * bfhi(ub.w);
    sa = sa2; sb = sb2;
  }
  den += __shfl_xor(den, 16, 64); den += __shfl_xor(den, 32, 64);
  a0 += __shfl_xor(a0, 16, 64); a0 += __shfl_xor(a0, 32, 64);
  a1 += __shfl_xor(a1, 16, 64); a1 += __shfl_xor(a1, 32, 64);
  a2 += __shfl_xor(a2, 16, 64); a2 += __shfl_xor(a2, 32, 64);
  a3 += __shfl_xor(a3, 16, 64); a3 += __shfl_xor(a3, 32, 64);
  a4 += __shfl_xor(a4, 16, 64); a4 += __shfl_xor(a4, 32, 64);
  a5 += __shfl_xor(a5, 16, 64); a5 += __shfl_xor(a5, 32, 64);
  a6 += __shfl_xor(a6, 16, 64); a6 += __shfl_xor(a6, 32, 64);
  a7 += __shfl_xor(a7, 16, 64); a7 += __shfl_xor(a7, 32, 64);
  float inv = 1.0f / den;
  if (g == 0) {
    float4 o = make_float4(a0 * inv, a1 * inv, a2 * inv, a3 * inv);
    *(float4*)&out[wid * DOUT + sl * 8] = o;
  } else if (g == 1) {
    float4 o = make_float4(a4 * inv, a5 * inv, a6 * inv, a7 * inv);
    *(float4*)&out[wid * DOUT + sl * 8 + 4] = o;
  }
}

extern "C" void kernel_launch(void* const* d_in, const int* in_sizes, int n_in,
                              void* d_out, int out_size, void* d_ws, size_t ws_size,
                              hipStream_t stream) {
  const float* x     = (const float*)d_in[0];
  const float* W     = (const float*)d_in[1];
  const float* Wa    = (const float*)d_in[2];
  const float* b_att = (const float*)d_in[3];
  const int*   ei    = (const int*)d_in[4];
  const int N  = in_sizes[0] / DIN;
  const int E  = in_sizes[4] / 2;
  const int NB = (N + 255) / 256;  // 196 buckets
  float* out = (float*)d_out;

  char* p = (char*)d_ws;
  auto take = [&p](size_t bytes) {
    uintptr_t u = ((uintptr_t)p + 15) & ~(uintptr_t)15;
    p = (char*)(u + bytes);
    return (void*)u;
  };
  unsigned short* hbf = (unsigned short*)take((size_t)N * DOUT * 2);
  unsigned short* Wbf = (unsigned short*)take((size_t)DOUT * DIN * 2);
  float* a_src        = (float*)take((size_t)N * H * 4);
  float* a_dst        = (float*)take((size_t)N * H * 4);
  int* bcount         = (int*)take((size_t)NB * 4);
  unsigned* pair_buf  = (unsigned*)take((size_t)NB * CAP * 4);
  int* offsets        = (int*)take((size_t)(N + 1) * 4);
  unsigned short* src_sorted = (unsigned short*)take((size_t)(E + N + 16) * 2);

  dim3 b256(256);
  const int bp_blocks   = (E + CHUNK - 1) / CHUNK;        // 391
  const int gemm_blocks = ((N + 31) / 32 + 3) / 4;        // 391 (4 waves x 32 rows)
  const int ns_blocks   = (N * H + 255) / 256;            // 1563

  conv_w<<<dim3((DOUT * DIN + 255) / 256), b256, 0, stream>>>(W, Wbf, DOUT * DIN, bcount, NB);
  bp_gemm<<<dim3(bp_blocks + gemm_blocks), b256, 0, stream>>>(
      x, Wbf, hbf, N, ei, bcount, pair_buf, E, NB, bp_blocks);
  fs_ns<<<dim3(NB + ns_blocks), b256, 0, stream>>>(
      pair_buf, bcount, offsets, src_sorted, hbf, Wa, a_src, a_dst, N, E, NB);
  aggregate<<<dim3((N + 3) / 4), b256, 0, stream>>>(hbf, a_src, a_dst, b_att, offsets,
                                                    src_sorted, out, N);
}